// Round 6
// baseline (279.125 us; speedup 1.0000x reference)
//
#include <hip/hip_runtime.h>
#include <stdint.h>

// ---- problem constants ----
#define DHW         13824      // 24*24*24 spatial positions per (b,c,g) plane
#define NCH         32         // channels C
#define NG          24         // octahedral group order
#define FEATC       72         // NG * N_SEL features per channel
#define KDIM        2304       // NCH * FEATC  (GEMM reduction dim)
#define NHEAD       64
#define TP          16         // spatial positions per block
#define KPITCH      2312       // feat LDS row pitch in bf16 (+8 pad)
#define TILES_PER_B 864        // DHW / TP
#define NTILES      1728       // B * TILES_PER_B
#define KSTEPS      72         // KDIM / 32
#define KHALF       36         // KSTEPS / 2
#define HCHUNK      6          // h-values per register chunk (4 chunks)

typedef __attribute__((ext_vector_type(2))) float    f32x2;
typedef __attribute__((ext_vector_type(8))) short    s16x8;
typedef __attribute__((ext_vector_type(4))) float    f32x4;

// ---- compile-time Cayley table of S4 (matches itertools.permutations order) ----
struct Tables { int cay[NG][NG]; int s1[NG]; int s2[NG]; };

constexpr Tables make_tables() {
    int perms[NG][4] = {};
    int n = 0;
    for (int a = 0; a < 4; ++a)
        for (int b = 0; b < 4; ++b) {
            if (b == a) continue;
            for (int c = 0; c < 4; ++c) {
                if (c == a || c == b) continue;
                int d = 6 - a - b - c;
                perms[n][0] = a; perms[n][1] = b; perms[n][2] = c; perms[n][3] = d;
                ++n;
            }
        }
    int si1 = 0, si2 = 0;
    for (int i = 0; i < NG; ++i) {
        if (perms[i][0] == 1 && perms[i][1] == 0 && perms[i][2] == 2 && perms[i][3] == 3) si1 = i;
        if (perms[i][0] == 1 && perms[i][1] == 2 && perms[i][2] == 3 && perms[i][3] == 0) si2 = i;
    }
    Tables t{};
    for (int p = 0; p < NG; ++p) {
        for (int q = 0; q < NG; ++q) {
            int c0 = perms[p][perms[q][0]];
            int c1 = perms[p][perms[q][1]];
            int c2 = perms[p][perms[q][2]];
            int c3 = perms[p][perms[q][3]];
            int r = 0;
            for (int i = 0; i < NG; ++i)
                if (perms[i][0] == c0 && perms[i][1] == c1 &&
                    perms[i][2] == c2 && perms[i][3] == c3) { r = i; break; }
            t.cay[p][q] = r;
        }
        t.s1[p] = t.cay[p][si1];
        t.s2[p] = t.cay[p][si2];
    }
    return t;
}
constexpr Tables TAB = make_tables();

__device__ __forceinline__ uint32_t f2bf(float f) {   // fp32 -> bf16 (RNE), u16 in low bits
    uint32_t u = __float_as_uint(f);
    u += 0x7fffu + ((u >> 16) & 1u);
    return u >> 16;
}

// ---- kernel 1: W (fp32 64x2304) -> bf16, pre-swizzled into MFMA A-fragment order.
// WbS[((ot*KSTEPS + kk)*64 + lane)*8 + j] = W[ot*16 + (lane&15)][kk*32 + (lane>>4)*8 + j]
__global__ __launch_bounds__(256) void prep_w(const float* __restrict__ W,
                                              unsigned short* __restrict__ WbS) {
    int i = blockIdx.x * 256 + threadIdx.x;
    if (i >= NHEAD * KDIM) return;
    int j  = i & 7;
    int t1 = i >> 3;
    int l  = t1 & 63;
    int t2 = t1 >> 6;
    int kk = t2 % KSTEPS;
    int ot = t2 / KSTEPS;
    int o = ot * 16 + (l & 15);
    int k = kk * 32 + ((l >> 4) << 3) + j;
    WbS[i] = (unsigned short)f2bf(W[o * KDIM + k]);
}

// ---- kernel 2: fused bispectrum + signed-log1p + ReLU + 64x2304 GEMM, 16 positions/block
// 512 threads (8 waves).
// R5 lesson: the 24 xf loads written as (per-thread 64-bit pointer + g*55296B offsets)
// need ~24 VGPR address PAIRS (offsets exceed the 13-bit imm) -> ~48 regs of addressing;
// under the 64-VGPR budget the compiler rematerialized the loads per chunk (FETCH scaled
// with chunk count: 141/268/584 MB) and spilled. Fix: uniform base pointer + divergent
// 32-bit element index -> SADDR-form global_load (1 VGPR index + 1 v_add per load).
// True peak live then ~52 regs: xf[24] + 6 tau0 + 12 tau12 + temps. HCHUNK=6 chunks,
// features packed+stored to LDS immediately, sched_barrier(0) pins chunk boundaries.
__global__ __launch_bounds__(512, 4)
void bispec_fused(
        const float* __restrict__ x,
        const unsigned short* __restrict__ WbS,
        const float* __restrict__ bias,
        float* __restrict__ y)
{
    __shared__ alignas(16) unsigned short featS[TP * KPITCH];   // 73,984 B

    const int bid = blockIdx.x;
    // XCD-chunked swizzle: consecutive tiles share an XCD's L2 (1728 % 8 == 0)
    const int swz = (bid & 7) * (NTILES / 8) + (bid >> 3);
    const int bb  = swz / TILES_PER_B;
    const int psp = (swz - bb * TILES_PER_B) * TP;
    const int tid = threadIdx.x;

    // ---------------- phase A: bispectrum features, 1 (c,p) row per thread ----------------
    {
        const int p0 = tid & 15;
        const int c0 = tid >> 4;                         // 0..31
        // 32-bit divergent index against the UNIFORM base x (max 21.2M elements < 2^31):
        // backend emits saddr-form global_load_dword (base in SGPR pair, index in 1 VGPR).
        const unsigned idx0 = (unsigned)(bb * NCH + c0) * (NG * DHW) + (unsigned)(psp + p0);
        float xf[NG];
        #pragma unroll
        for (int g = 0; g < NG; ++g) xf[g] = x[idx0 + (unsigned)(g * DHW)];

        // dword-indexed LDS destination for this row's 72 features (144 B, dword-aligned)
        uint32_t* dstw = (uint32_t*)((char*)featS + p0 * (KPITCH * 2) + c0 * (FEATC * 2));

        #pragma unroll
        for (int ch = 0; ch < NG / HCHUNK; ++ch) {
            float tau0[HCHUNK];          // s = identity component
            f32x2 tau12[HCHUNK];         // (s1, s2) components -> v_pk_fma_f32
            #pragma unroll
            for (int hh = 0; hh < HCHUNK; ++hh) { tau0[hh] = 0.f; tau12[hh] = (f32x2){0.f, 0.f}; }
            #pragma unroll
            for (int g = 0; g < NG; ++g) {
                const float xg = xf[g];
                const float q0 = xg * xg;
                const f32x2 q12 = {xg * xf[TAB.s1[g]], xg * xf[TAB.s2[g]]};
                #pragma unroll
                for (int hh = 0; hh < HCHUNK; ++hh) {
                    const float v = xf[TAB.cay[g][ch * HCHUNK + hh]];   // static reg index
                    tau0[hh] = fmaf(q0, v, tau0[hh]);
                    tau12[hh] = __builtin_elementwise_fma((f32x2){v, v}, q12, tau12[hh]);
                }
            }
            // relu(sign*log1p(|t|)) == (t>0 ? log(1+t) : 0); pack each 2-h group to
            // 3 bf16-pair words and store NOW (12 B, dword-aligned) so they die instantly.
            #pragma unroll
            for (int hh = 0; hh < HCHUNK; hh += 2) {
                float f0 = tau0[hh]       > 0.f ? __logf(1.f + tau0[hh])       : 0.f;
                float f1 = tau12[hh][0]   > 0.f ? __logf(1.f + tau12[hh][0])   : 0.f;
                float f2 = tau12[hh][1]   > 0.f ? __logf(1.f + tau12[hh][1])   : 0.f;
                float f3 = tau0[hh+1]     > 0.f ? __logf(1.f + tau0[hh+1])     : 0.f;
                float f4 = tau12[hh+1][0] > 0.f ? __logf(1.f + tau12[hh+1][0]) : 0.f;
                float f5 = tau12[hh+1][1] > 0.f ? __logf(1.f + tau12[hh+1][1]) : 0.f;
                const int bw = ch * (HCHUNK / 2) * 3 + (hh >> 1) * 3;
                dstw[bw + 0] = f2bf(f0) | (f2bf(f1) << 16);
                dstw[bw + 1] = f2bf(f2) | (f2bf(f3) << 16);
                dstw[bw + 2] = f2bf(f4) | (f2bf(f5) << 16);
            }
            // pin chunk ordering: stop the scheduler merging chunks (register pressure)
            __builtin_amdgcn_sched_barrier(0);
        }
    }
    __syncthreads();

    // ---------------- phase B: y[64 x 16] = W @ feat, K split across wave pairs ----------------
    const int w  = tid >> 6;          // wave 0..7
    const int ot = w & 3;             // o-tile (16 heads)
    const int kh = w >> 2;            // K half
    const int l  = tid & 63;
    const int ln = l & 15;            // position col
    const int lh = l >> 4;            // k sub-block

    f32x4 acc0 = {0.f, 0.f, 0.f, 0.f};
    f32x4 acc1 = {0.f, 0.f, 0.f, 0.f};
    const s16x8* wbase = (const s16x8*)WbS + ((size_t)(ot * KSTEPS + kh * KHALF) * 64 + l);
    const unsigned short* fb = &featS[ln * KPITCH + kh * KHALF * 32 + lh * 8];

    #pragma unroll 3
    for (int kk = 0; kk < KHALF; kk += 2) {
        s16x8 a0 = wbase[(size_t)kk * 64];
        s16x8 b0 = *(const s16x8*)(fb + kk * 32);
        acc0 = __builtin_amdgcn_mfma_f32_16x16x32_bf16(a0, b0, acc0, 0, 0, 0);
        s16x8 a1 = wbase[(size_t)(kk + 1) * 64];
        s16x8 b1 = *(const s16x8*)(fb + (kk + 1) * 32);
        acc1 = __builtin_amdgcn_mfma_f32_16x16x32_bf16(a1, b1, acc1, 0, 0, 0);
    }
    f32x4 acc = acc0 + acc1;

    // reduce wave pairs through LDS (featS is dead now), then write
    f32x4* redS = (f32x4*)featS;      // 4 o-tiles x 64 lanes x 16B = 4 KB
    __syncthreads();
    if (kh == 1) redS[ot * 64 + l] = acc;
    __syncthreads();
    if (kh == 0) {
        acc += redS[ot * 64 + l];
        const size_t ybase = (size_t)bb * NHEAD * DHW + (size_t)(psp + ln);
        #pragma unroll
        for (int j = 0; j < 4; ++j) {
            const int o = ot * 16 + lh * 4 + j;
            y[ybase + (size_t)o * DHW] = acc[j] + bias[o];
        }
    }
}

extern "C" void kernel_launch(void* const* d_in, const int* in_sizes, int n_in,
                              void* d_out, int out_size, void* d_ws, size_t ws_size,
                              hipStream_t stream) {
    const float* x    = (const float*)d_in[0];
    const float* W    = (const float*)d_in[1];
    const float* bias = (const float*)d_in[2];
    unsigned short* WbS = (unsigned short*)d_ws;   // 64*2304*2 = 294,912 B

    prep_w<<<dim3((NHEAD * KDIM + 255) / 256), dim3(256), 0, stream>>>(W, WbS);
    bispec_fused<<<dim3(NTILES), dim3(512), 0, stream>>>(x, WbS, bias, (float*)d_out);
}

// Round 7
// 85.509 us; speedup vs baseline: 3.2643x; 3.2643x over previous
//
#include <hip/hip_runtime.h>
#include <stdint.h>

// ---- problem constants ----
#define DHW         13824      // 24*24*24 spatial positions per (b,c,g) plane
#define NCH         32         // channels C
#define NG          24         // octahedral group order
#define FEATC       72         // NG * N_SEL features per channel
#define KDIM        2304       // NCH * FEATC  (GEMM reduction dim)
#define NHEAD       64
#define TP          16         // spatial positions per block
#define KPITCH      2312       // feat LDS row pitch in bf16 (+8 pad, rows 16B-aligned)
#define TILES_PER_B 864        // DHW / TP
#define NTILES      1728       // B * TILES_PER_B
#define KSTEPS      72         // KDIM / 32

typedef __attribute__((ext_vector_type(2))) float    f32x2;
typedef __attribute__((ext_vector_type(8))) short    s16x8;
typedef __attribute__((ext_vector_type(4))) float    f32x4;
typedef __attribute__((ext_vector_type(4))) uint32_t u32x4;

// ---- compile-time Cayley table of S4 (matches itertools.permutations order) ----
struct Tables { int cay[NG][NG]; int s1[NG]; int s2[NG]; };

constexpr Tables make_tables() {
    int perms[NG][4] = {};
    int n = 0;
    for (int a = 0; a < 4; ++a)
        for (int b = 0; b < 4; ++b) {
            if (b == a) continue;
            for (int c = 0; c < 4; ++c) {
                if (c == a || c == b) continue;
                int d = 6 - a - b - c;
                perms[n][0] = a; perms[n][1] = b; perms[n][2] = c; perms[n][3] = d;
                ++n;
            }
        }
    int si1 = 0, si2 = 0;
    for (int i = 0; i < NG; ++i) {
        if (perms[i][0] == 1 && perms[i][1] == 0 && perms[i][2] == 2 && perms[i][3] == 3) si1 = i;
        if (perms[i][0] == 1 && perms[i][1] == 2 && perms[i][2] == 3 && perms[i][3] == 0) si2 = i;
    }
    Tables t{};
    for (int p = 0; p < NG; ++p) {
        for (int q = 0; q < NG; ++q) {
            int c0 = perms[p][perms[q][0]];
            int c1 = perms[p][perms[q][1]];
            int c2 = perms[p][perms[q][2]];
            int c3 = perms[p][perms[q][3]];
            int r = 0;
            for (int i = 0; i < NG; ++i)
                if (perms[i][0] == c0 && perms[i][1] == c1 &&
                    perms[i][2] == c2 && perms[i][3] == c3) { r = i; break; }
            t.cay[p][q] = r;
        }
        t.s1[p] = t.cay[p][si1];
        t.s2[p] = t.cay[p][si2];
    }
    return t;
}
constexpr Tables TAB = make_tables();

__device__ __forceinline__ uint32_t f2bf(float f) {   // fp32 -> bf16 (RNE), u16 in low bits
    uint32_t u = __float_as_uint(f);
    u += 0x7fffu + ((u >> 16) & 1u);
    return u >> 16;
}

// ---- kernel 1: W (fp32 64x2304) -> bf16, pre-swizzled into MFMA A-fragment order.
// WbS[((ot*KSTEPS + kk)*64 + lane)*8 + j] = W[ot*16 + (lane&15)][kk*32 + (lane>>4)*8 + j]
__global__ __launch_bounds__(256) void prep_w(const float* __restrict__ W,
                                              unsigned short* __restrict__ WbS) {
    int i = blockIdx.x * 256 + threadIdx.x;
    if (i >= NHEAD * KDIM) return;
    int j  = i & 7;
    int t1 = i >> 3;
    int l  = t1 & 63;
    int t2 = t1 >> 6;
    int kk = t2 % KSTEPS;
    int ot = t2 / KSTEPS;
    int o = ot * 16 + (l & 15);
    int k = kk * 32 + ((l >> 4) << 3) + j;
    WbS[i] = (unsigned short)f2bf(W[o * KDIM + k]);
}

// ---- kernel 2: fused bispectrum + signed-log1p + ReLU + 64x2304 GEMM, 16 positions/block
// 256 threads (4 waves). R1-R6 lesson: 512-thread blocks get pinned at 64 VGPRs and the
// ~100-live-float phase A spills/rematerializes (300-600 MB of scratch HBM traffic).
// 256-thread blocks empirically get 128 VGPRs (R1). One row/thread needs ~100 live
// (24 xf + 72 tau + temps) -> fits 128 with slack. TP=16 keeps 512 rows/block, so
// phase A runs TWO sequential passes (pass p: channels 16p..16p+15), one row each,
// separated by sched_barrier(0) so the passes' live ranges can't merge. Each row is
// loaded and consumed exactly once: no redundant work, no remat incentive.
__global__ __launch_bounds__(256, 2)
void bispec_fused(
        const float* __restrict__ x,
        const unsigned short* __restrict__ WbS,
        const float* __restrict__ bias,
        float* __restrict__ y)
{
    __shared__ alignas(16) unsigned short featS[TP * KPITCH];   // 73,984 B

    const int bid = blockIdx.x;
    // XCD-chunked swizzle: consecutive tiles share an XCD's L2 (1728 % 8 == 0)
    const int swz = (bid & 7) * (NTILES / 8) + (bid >> 3);
    const int bb  = swz / TILES_PER_B;
    const int psp = (swz - bb * TILES_PER_B) * TP;
    const int tid = threadIdx.x;

    // ---------------- phase A: bispectrum features, 2 passes x 1 (c,p) row ----------------
    {
        const int p0    = tid & 15;
        const int cbase = tid >> 4;                      // 0..15
        #pragma unroll
        for (int pass = 0; pass < 2; ++pass) {
            const int c0 = cbase + pass * 16;
            // 32-bit divergent index vs uniform base -> saddr-form global_load_dword
            const unsigned idx0 = (unsigned)(bb * NCH + c0) * (NG * DHW) + (unsigned)(psp + p0);
            float xf[NG];
            #pragma unroll
            for (int g = 0; g < NG; ++g) xf[g] = x[idx0 + (unsigned)(g * DHW)];

            float tau0[NG];          // s = identity component
            f32x2 tau12[NG];         // (s1, s2) components -> v_pk_fma_f32
            #pragma unroll
            for (int h = 0; h < NG; ++h) { tau0[h] = 0.f; tau12[h] = (f32x2){0.f, 0.f}; }
            #pragma unroll
            for (int g = 0; g < NG; ++g) {
                const float xg = xf[g];
                const float q0 = xg * xg;
                const f32x2 q12 = {xg * xf[TAB.s1[g]], xg * xf[TAB.s2[g]]};
                #pragma unroll
                for (int h = 0; h < NG; ++h) {
                    const float v = xf[TAB.cay[g][h]];   // static register index
                    tau0[h] = fmaf(q0, v, tau0[h]);
                    tau12[h] = __builtin_elementwise_fma((f32x2){v, v}, q12, tau12[h]);
                }
            }
            // relu(sign*log1p(|t|)) == (t>0 ? log(1+t) : 0); pack bf16 pairs
            uint32_t pk[FEATC / 2];
            #pragma unroll
            for (int h = 0; h < NG; h += 2) {
                float f0 = tau0[h]      > 0.f ? __logf(1.f + tau0[h])      : 0.f;
                float f1 = tau12[h][0]  > 0.f ? __logf(1.f + tau12[h][0])  : 0.f;
                float f2 = tau12[h][1]  > 0.f ? __logf(1.f + tau12[h][1])  : 0.f;
                float f3 = tau0[h+1]    > 0.f ? __logf(1.f + tau0[h+1])    : 0.f;
                float f4 = tau12[h+1][0]> 0.f ? __logf(1.f + tau12[h+1][0]): 0.f;
                float f5 = tau12[h+1][1]> 0.f ? __logf(1.f + tau12[h+1][1]): 0.f;
                const int bw = (h >> 1) * 3;
                pk[bw + 0] = f2bf(f0) | (f2bf(f1) << 16);
                pk[bw + 1] = f2bf(f2) | (f2bf(f3) << 16);
                pk[bw + 2] = f2bf(f4) | (f2bf(f5) << 16);
            }
            uint32_t* dst = (uint32_t*)&featS[p0 * KPITCH + c0 * FEATC];  // 16B-aligned
            #pragma unroll
            for (int i = 0; i < FEATC / 2; i += 4) {
                u32x4 v; v[0] = pk[i]; v[1] = pk[i+1]; v[2] = pk[i+2]; v[3] = pk[i+3];
                *(u32x4*)(dst + i) = v;
            }
            // keep the two passes' live ranges disjoint (register pressure)
            __builtin_amdgcn_sched_barrier(0);
        }
    }
    __syncthreads();

    // ---------------- phase B: y[64 x 16] = W @ feat via MFMA 16x16x32 bf16 ----------------
    const int wv = tid >> 6;          // wave -> o-tile (16 heads)
    const int l  = tid & 63;
    const int ln = l & 15;            // position col
    const int lh = l >> 4;            // k sub-block

    f32x4 acc0 = {0.f, 0.f, 0.f, 0.f};
    f32x4 acc1 = {0.f, 0.f, 0.f, 0.f};
    const s16x8* wbase = (const s16x8*)WbS + ((size_t)wv * KSTEPS * 64 + l);
    const unsigned short* fb = &featS[ln * KPITCH + lh * 8];

    #pragma unroll 4
    for (int kk = 0; kk < KSTEPS; kk += 2) {
        s16x8 a0 = wbase[(size_t)kk * 64];
        s16x8 b0 = *(const s16x8*)(fb + kk * 32);
        acc0 = __builtin_amdgcn_mfma_f32_16x16x32_bf16(a0, b0, acc0, 0, 0, 0);
        s16x8 a1 = wbase[(size_t)(kk + 1) * 64];
        s16x8 b1 = *(const s16x8*)(fb + (kk + 1) * 32);
        acc1 = __builtin_amdgcn_mfma_f32_16x16x32_bf16(a1, b1, acc1, 0, 0, 0);
    }

    // D layout: col = lane&15 (position), row = (lane>>4)*4 + j (head within o-tile)
    const size_t ybase = (size_t)bb * NHEAD * DHW + (size_t)(psp + ln);
    #pragma unroll
    for (int j = 0; j < 4; ++j) {
        const int o = wv * 16 + lh * 4 + j;
        y[ybase + (size_t)o * DHW] = acc0[j] + acc1[j] + bias[o];
    }
}

extern "C" void kernel_launch(void* const* d_in, const int* in_sizes, int n_in,
                              void* d_out, int out_size, void* d_ws, size_t ws_size,
                              hipStream_t stream) {
    const float* x    = (const float*)d_in[0];
    const float* W    = (const float*)d_in[1];
    const float* bias = (const float*)d_in[2];
    unsigned short* WbS = (unsigned short*)d_ws;   // 64*2304*2 = 294,912 B

    prep_w<<<dim3((NHEAD * KDIM + 255) / 256), dim3(256), 0, stream>>>(W, WbS);
    bispec_fused<<<dim3(NTILES), dim3(256), 0, stream>>>(x, WbS, bias, (float*)d_out);
}